// Round 9
// baseline (176.317 us; speedup 1.0000x reference)
//
#include <hip/hip_runtime.h>

typedef float  f32x2  __attribute__((ext_vector_type(2)));
typedef float  f32x4  __attribute__((ext_vector_type(4)));
typedef float  f32x16 __attribute__((ext_vector_type(16)));
typedef short  s16x4  __attribute__((ext_vector_type(4)));
typedef short  s16x8  __attribute__((ext_vector_type(8)));
typedef unsigned int u32x2 __attribute__((ext_vector_type(2)));

__device__ __forceinline__ unsigned f2bf(float f) {
    unsigned u = __builtin_bit_cast(unsigned, f);
    u += 0x7FFFu + ((u >> 16) & 1u);   // RNE
    return u >> 16;
}
__device__ __forceinline__ s16x4 pack4(float a, float b, float c, float d) {
    u32x2 u;
    u[0] = f2bf(a) | (f2bf(b) << 16);
    u[1] = f2bf(c) | (f2bf(d) << 16);
    return __builtin_bit_cast(s16x4, u);
}
__device__ __forceinline__ s16x4 pack4v(f32x4 v) { return pack4(v[0], v[1], v[2], v[3]); }
__device__ __forceinline__ s16x4 lo4(s16x8 v) { return __builtin_shufflevector(v, v, 0, 1, 2, 3); }
__device__ __forceinline__ s16x4 hi4(s16x8 v) { return __builtin_shufflevector(v, v, 4, 5, 6, 7); }

// ---------------------------------------------------------------------------
// Node MLP (unchanged, proven): P = relu(relu(X W1^T+b1) W2^T+b2) Wm^T (+ bm),
// bf16 out, natural channel layout P[node*32+ch]. 32x32x8 MFMA path.
// ---------------------------------------------------------------------------
__device__ __forceinline__ void node_body(
    const float* __restrict__ X,
    const float* __restrict__ W1, const float* __restrict__ b1,
    const float* __restrict__ W2, const float* __restrict__ b2,
    const float* __restrict__ Wm, const float* __restrict__ bm,
    unsigned short* __restrict__ outp, int N, int tile0)
{
    const int lane = threadIdx.x & 63;
    const int g = lane >> 5, m = lane & 31;
    const int ntile = (N + 31) >> 5;
    if (tile0 >= ntile) return;

    s16x4 a1[4], a2[4], am[4];
#pragma unroll
    for (int q = 0; q < 4; ++q) {
        const float* p1 = W1 + m * 32 + 8 * q + 4 * g;
        a1[q] = pack4(p1[0], p1[1], p1[2], p1[3]);
        const float* p2 = W2 + m * 32 + 8 * q + 4 * g;
        a2[q] = pack4(p2[0], p2[1], p2[2], p2[3]);
        const float* pm = Wm + m * 96 + 8 * q + 4 * g;
        am[q] = pack4(pm[0], pm[1], pm[2], pm[3]);
    }
    f32x16 f1, f2, f3;
#pragma unroll
    for (int r = 0; r < 16; ++r) {
        int ch = (r & 3) + 8 * (r >> 2) + 4 * g;
        f1[r] = b1[ch];
        f2[r] = b2[ch];
        f3[r] = bm ? bm[ch] : 0.f;
    }

#pragma unroll
    for (int k = 0; k < 4; ++k) {
        const int tile = tile0 + k;
        if (tile >= ntile) break;
        const int node0 = tile * 32 + m;
        const int node = node0 < N ? node0 : N - 1;

        s16x4 bX[4];
#pragma unroll
        for (int q = 0; q < 4; ++q) {
            f32x4 v = *reinterpret_cast<const f32x4*>(X + (size_t)node * 32 + 8 * q + 4 * g);
            bX[q] = pack4v(v);
        }
        f32x16 acc = f1;
#pragma unroll
        for (int q = 0; q < 4; ++q) acc = __builtin_amdgcn_mfma_f32_32x32x8bf16_1k(a1[q], bX[q], acc, 0, 0, 0);
        s16x4 bH[4];
#pragma unroll
        for (int q = 0; q < 4; ++q)
            bH[q] = pack4(fmaxf(acc[4*q+0], 0.f), fmaxf(acc[4*q+1], 0.f),
                          fmaxf(acc[4*q+2], 0.f), fmaxf(acc[4*q+3], 0.f));
        acc = f2;
#pragma unroll
        for (int q = 0; q < 4; ++q) acc = __builtin_amdgcn_mfma_f32_32x32x8bf16_1k(a2[q], bH[q], acc, 0, 0, 0);
#pragma unroll
        for (int q = 0; q < 4; ++q)
            bH[q] = pack4(fmaxf(acc[4*q+0], 0.f), fmaxf(acc[4*q+1], 0.f),
                          fmaxf(acc[4*q+2], 0.f), fmaxf(acc[4*q+3], 0.f));
        acc = f3;
#pragma unroll
        for (int q = 0; q < 4; ++q) acc = __builtin_amdgcn_mfma_f32_32x32x8bf16_1k(am[q], bH[q], acc, 0, 0, 0);

        if (node0 < N) {
#pragma unroll
            for (int q = 0; q < 4; ++q) {
                s16x4 o = pack4(acc[4*q+0], acc[4*q+1], acc[4*q+2], acc[4*q+3]);
                *reinterpret_cast<s16x4*>(outp + (size_t)node0 * 32 + 8 * q + 4 * g) = o;
            }
        }
    }
}

__global__ __launch_bounds__(256) void nodes_kernel(
    const float* __restrict__ var_f, const float* __restrict__ con_f,
    const float* __restrict__ Wv1, const float* __restrict__ bv1,
    const float* __restrict__ Wv2, const float* __restrict__ bv2,
    const float* __restrict__ Wc1, const float* __restrict__ bc1,
    const float* __restrict__ Wc2, const float* __restrict__ bc2,
    const float* __restrict__ We1, const float* __restrict__ be1,
    unsigned short* __restrict__ pv, unsigned short* __restrict__ pc,
    int nV, int nC, int wavesV)
{
    const int wvg = (blockIdx.x * blockDim.x + threadIdx.x) >> 6;
    if (wvg < wavesV) {
        node_body(var_f, Wv1, bv1, Wv2, bv2, We1 + 32, be1, pv, nV, wvg * 4);
    } else {
        node_body(con_f, Wc1, bc1, Wc2, bc2, We1 + 64, nullptr, pc, nC,
                  (wvg - wavesV) * 4);
    }
}

// ---------------------------------------------------------------------------
// Edge kernel, 16x16x16 MFMA, edges-as-COLUMNS (R8 structure) with the LDS
// store-transpose REMOVED: in this layout the D-fragment store
// out[(32t+16e+m)*32 + 16r + 4c] is already fully line-coalesced (4 lanes
// cover each 64B line; the r=0/1 pair covers each 128B row). No LDS at all.
// Depth-1 pipeline for Ef/gathers/idx as before; NT stores.
// ---------------------------------------------------------------------------
__global__ __launch_bounds__(256, 4) void edge_kernel(
    const float* __restrict__ Ef, const int* __restrict__ idx,
    const unsigned short* __restrict__ pv, const unsigned short* __restrict__ pc,
    const float* __restrict__ We1, const float* __restrict__ We2,
    const float* __restrict__ be2,
    float* __restrict__ out, int nE)
{
    const int lane = threadIdx.x & 63;
    const int m = lane & 15, c = lane >> 4;   // 16x16 frag coords

    // Weight fragments (16x16x16): A[row=l%16][k=4c+j].
    s16x4 aW1[2][2], aP[2][2], aW2[2][2];
    f32x4 b2f[2];
#pragma unroll
    for (int r = 0; r < 2; ++r) {
#pragma unroll
        for (int kk = 0; kk < 2; ++kk) {
            const float* p1 = We1 + (16 * r + m) * 96 + 16 * kk + 4 * c;
            aW1[r][kk] = pack4(p1[0], p1[1], p1[2], p1[3]);
            const float* p2 = We2 + (16 * r + m) * 32 + 16 * kk + 4 * c;
            aW2[r][kk] = pack4(p2[0], p2[1], p2[2], p2[3]);
            const int j_hit = 16 * r + m - 8 * c - 4 * kk;
            s16x4 w;
#pragma unroll
            for (int j = 0; j < 4; ++j) w[j] = (short)((j == j_hit) ? 0x3F80 : 0);
            aP[r][kk] = w;
        }
        f32x4 b;
#pragma unroll
        for (int j = 0; j < 4; ++j) b[j] = be2[16 * r + 4 * c + j];
        b2f[r] = b;
    }

    const int ntile = nE >> 5;
    const int nw = (gridDim.x * blockDim.x) >> 6;
    int t = (blockIdx.x * blockDim.x + threadIdx.x) >> 6;
    if (t >= ntile) return;

    // ---- prologue: stage tile t ----
    int ib0[2], ib1[2];          // idx for the NEXT staged tile
    s16x4 ebf[2][2];             // Ef bf16 frags, current tile
    s16x8 pvf[2], pcf[2];        // gathered partials, current tile
    {
        int i0[2], i1[2];
#pragma unroll
        for (int e = 0; e < 2; ++e) {
            i0[e] = idx[t * 32 + 16 * e + m];
            i1[e] = idx[nE + t * 32 + 16 * e + m];
        }
#pragma unroll
        for (int e = 0; e < 2; ++e) {
#pragma unroll
            for (int kk = 0; kk < 2; ++kk) {
                f32x4 v = *reinterpret_cast<const f32x4*>(
                    Ef + (size_t)(t * 32 + 16 * e + m) * 32 + 16 * kk + 4 * c);
                ebf[e][kk] = pack4v(v);
            }
            pvf[e] = *reinterpret_cast<const s16x8*>(pv + (size_t)i0[e] * 32 + 8 * c);
            pcf[e] = *reinterpret_cast<const s16x8*>(pc + (size_t)i1[e] * 32 + 8 * c);
        }
        int t1 = (t + nw < ntile) ? t + nw : t;
#pragma unroll
        for (int e = 0; e < 2; ++e) {
            ib0[e] = idx[t1 * 32 + 16 * e + m];
            ib1[e] = idx[nE + t1 * 32 + 16 * e + m];
        }
    }

    while (true) {
        const int tn = t + nw;
        const int tc = tn < ntile ? tn : t;

        // ---- issue stage(t+nw): Ef (f32), gathers, idx(t+2nw) ----
        f32x4 nef[2][2];
        s16x8 npv[2], npc[2];
        int ic0[2], ic1[2];
#pragma unroll
        for (int e = 0; e < 2; ++e) {
#pragma unroll
            for (int kk = 0; kk < 2; ++kk)
                nef[e][kk] = *reinterpret_cast<const f32x4*>(
                    Ef + (size_t)(tc * 32 + 16 * e + m) * 32 + 16 * kk + 4 * c);
            npv[e] = *reinterpret_cast<const s16x8*>(pv + (size_t)ib0[e] * 32 + 8 * c);
            npc[e] = *reinterpret_cast<const s16x8*>(pc + (size_t)ib1[e] * 32 + 8 * c);
        }
        {
            int t2 = (tn + nw < ntile) ? tn + nw : tc;
#pragma unroll
            for (int e = 0; e < 2; ++e) {
                ic0[e] = idx[t2 * 32 + 16 * e + m];
                ic1[e] = idx[nE + t2 * 32 + 16 * e + m];
            }
        }

        // ---- layer 1: acc[r][e], K=96 (Ef 2kk + pv perm + pc perm) ----
        f32x4 a00 = {}, a01 = {}, a10 = {}, a11 = {};
        a00 = __builtin_amdgcn_mfma_f32_16x16x16bf16_1k(aW1[0][0], ebf[0][0], a00, 0, 0, 0);
        a01 = __builtin_amdgcn_mfma_f32_16x16x16bf16_1k(aW1[0][0], ebf[1][0], a01, 0, 0, 0);
        a10 = __builtin_amdgcn_mfma_f32_16x16x16bf16_1k(aW1[1][0], ebf[0][0], a10, 0, 0, 0);
        a11 = __builtin_amdgcn_mfma_f32_16x16x16bf16_1k(aW1[1][0], ebf[1][0], a11, 0, 0, 0);
        a00 = __builtin_amdgcn_mfma_f32_16x16x16bf16_1k(aW1[0][1], ebf[0][1], a00, 0, 0, 0);
        a01 = __builtin_amdgcn_mfma_f32_16x16x16bf16_1k(aW1[0][1], ebf[1][1], a01, 0, 0, 0);
        a10 = __builtin_amdgcn_mfma_f32_16x16x16bf16_1k(aW1[1][1], ebf[0][1], a10, 0, 0, 0);
        a11 = __builtin_amdgcn_mfma_f32_16x16x16bf16_1k(aW1[1][1], ebf[1][1], a11, 0, 0, 0);
        a00 = __builtin_amdgcn_mfma_f32_16x16x16bf16_1k(aP[0][0], lo4(pvf[0]), a00, 0, 0, 0);
        a00 = __builtin_amdgcn_mfma_f32_16x16x16bf16_1k(aP[0][1], hi4(pvf[0]), a00, 0, 0, 0);
        a01 = __builtin_amdgcn_mfma_f32_16x16x16bf16_1k(aP[0][0], lo4(pvf[1]), a01, 0, 0, 0);
        a01 = __builtin_amdgcn_mfma_f32_16x16x16bf16_1k(aP[0][1], hi4(pvf[1]), a01, 0, 0, 0);
        a10 = __builtin_amdgcn_mfma_f32_16x16x16bf16_1k(aP[1][0], lo4(pvf[0]), a10, 0, 0, 0);
        a10 = __builtin_amdgcn_mfma_f32_16x16x16bf16_1k(aP[1][1], hi4(pvf[0]), a10, 0, 0, 0);
        a11 = __builtin_amdgcn_mfma_f32_16x16x16bf16_1k(aP[1][0], lo4(pvf[1]), a11, 0, 0, 0);
        a11 = __builtin_amdgcn_mfma_f32_16x16x16bf16_1k(aP[1][1], hi4(pvf[1]), a11, 0, 0, 0);
        a00 = __builtin_amdgcn_mfma_f32_16x16x16bf16_1k(aP[0][0], lo4(pcf[0]), a00, 0, 0, 0);
        a00 = __builtin_amdgcn_mfma_f32_16x16x16bf16_1k(aP[0][1], hi4(pcf[0]), a00, 0, 0, 0);
        a01 = __builtin_amdgcn_mfma_f32_16x16x16bf16_1k(aP[0][0], lo4(pcf[1]), a01, 0, 0, 0);
        a01 = __builtin_amdgcn_mfma_f32_16x16x16bf16_1k(aP[0][1], hi4(pcf[1]), a01, 0, 0, 0);
        a10 = __builtin_amdgcn_mfma_f32_16x16x16bf16_1k(aP[1][0], lo4(pcf[0]), a10, 0, 0, 0);
        a10 = __builtin_amdgcn_mfma_f32_16x16x16bf16_1k(aP[1][1], hi4(pcf[0]), a10, 0, 0, 0);
        a11 = __builtin_amdgcn_mfma_f32_16x16x16bf16_1k(aP[1][0], lo4(pcf[1]), a11, 0, 0, 0);
        a11 = __builtin_amdgcn_mfma_f32_16x16x16bf16_1k(aP[1][1], hi4(pcf[1]), a11, 0, 0, 0);

        // ---- relu + pack: bH[e][kk] <- acc[r=kk][e] ----
        s16x4 bH00 = pack4(fmaxf(a00[0], 0.f), fmaxf(a00[1], 0.f), fmaxf(a00[2], 0.f), fmaxf(a00[3], 0.f));
        s16x4 bH01 = pack4(fmaxf(a10[0], 0.f), fmaxf(a10[1], 0.f), fmaxf(a10[2], 0.f), fmaxf(a10[3], 0.f));
        s16x4 bH10 = pack4(fmaxf(a01[0], 0.f), fmaxf(a01[1], 0.f), fmaxf(a01[2], 0.f), fmaxf(a01[3], 0.f));
        s16x4 bH11 = pack4(fmaxf(a11[0], 0.f), fmaxf(a11[1], 0.f), fmaxf(a11[2], 0.f), fmaxf(a11[3], 0.f));

        // ---- layer 2: o[r][e] = be2 + We2 * H ----
        f32x4 o00 = b2f[0], o01 = b2f[0], o10 = b2f[1], o11 = b2f[1];
        o00 = __builtin_amdgcn_mfma_f32_16x16x16bf16_1k(aW2[0][0], bH00, o00, 0, 0, 0);
        o01 = __builtin_amdgcn_mfma_f32_16x16x16bf16_1k(aW2[0][0], bH10, o01, 0, 0, 0);
        o10 = __builtin_amdgcn_mfma_f32_16x16x16bf16_1k(aW2[1][0], bH00, o10, 0, 0, 0);
        o11 = __builtin_amdgcn_mfma_f32_16x16x16bf16_1k(aW2[1][0], bH10, o11, 0, 0, 0);
        o00 = __builtin_amdgcn_mfma_f32_16x16x16bf16_1k(aW2[0][1], bH01, o00, 0, 0, 0);
        o01 = __builtin_amdgcn_mfma_f32_16x16x16bf16_1k(aW2[0][1], bH11, o01, 0, 0, 0);
        o10 = __builtin_amdgcn_mfma_f32_16x16x16bf16_1k(aW2[1][1], bH01, o10, 0, 0, 0);
        o11 = __builtin_amdgcn_mfma_f32_16x16x16bf16_1k(aW2[1][1], bH11, o11, 0, 0, 0);

        // ---- store: direct, fully line-coalesced NT stores (no LDS) ----
        {
            float* obase = out + (size_t)(t * 32) * 32;
            __builtin_nontemporal_store(o00, reinterpret_cast<f32x4*>(obase + (16 * 0 + m) * 32 + 16 * 0 + 4 * c));
            __builtin_nontemporal_store(o10, reinterpret_cast<f32x4*>(obase + (16 * 0 + m) * 32 + 16 * 1 + 4 * c));
            __builtin_nontemporal_store(o01, reinterpret_cast<f32x4*>(obase + (16 * 1 + m) * 32 + 16 * 0 + 4 * c));
            __builtin_nontemporal_store(o11, reinterpret_cast<f32x4*>(obase + (16 * 1 + m) * 32 + 16 * 1 + 4 * c));
        }

        if (tn >= ntile) break;
        t = tn;
#pragma unroll
        for (int e = 0; e < 2; ++e) {
#pragma unroll
            for (int kk = 0; kk < 2; ++kk) ebf[e][kk] = pack4v(nef[e][kk]);
            pvf[e] = npv[e]; pcf[e] = npc[e];
            ib0[e] = ic0[e]; ib1[e] = ic1[e];
        }
    }
}

extern "C" void kernel_launch(void* const* d_in, const int* in_sizes, int n_in,
                              void* d_out, int out_size, void* d_ws, size_t ws_size,
                              hipStream_t stream) {
    const float* var_f = (const float*)d_in[0];
    const float* con_f = (const float*)d_in[1];
    const float* Ef    = (const float*)d_in[2];
    const int*   idx   = (const int*)d_in[3];
    const float* Wv1 = (const float*)d_in[4];
    const float* bv1 = (const float*)d_in[5];
    const float* Wv2 = (const float*)d_in[6];
    const float* bv2 = (const float*)d_in[7];
    const float* Wc1 = (const float*)d_in[8];
    const float* bc1 = (const float*)d_in[9];
    const float* Wc2 = (const float*)d_in[10];
    const float* bc2 = (const float*)d_in[11];
    const float* We1 = (const float*)d_in[12];
    const float* be1 = (const float*)d_in[13];
    const float* We2 = (const float*)d_in[14];
    const float* be2 = (const float*)d_in[15];
    float* out = (float*)d_out;

    const int nV = in_sizes[0] / 32;
    const int nC = in_sizes[1] / 32;
    const int nE = in_sizes[2] / 32;

    unsigned short* pv = (unsigned short*)d_ws;
    unsigned short* pc = pv + (size_t)nV * 32;

    const int wavesV = (((nV + 31) >> 5) + 3) >> 2;
    const int wavesC = (((nC + 31) >> 5) + 3) >> 2;
    const int nodeBlocks = (wavesV + wavesC + 3) / 4;
    nodes_kernel<<<nodeBlocks, 256, 0, stream>>>(
        var_f, con_f, Wv1, bv1, Wv2, bv2, Wc1, bc1, Wc2, bc2,
        We1, be1, pv, pc, nV, nC, wavesV);

    edge_kernel<<<2048, 256, 0, stream>>>(Ef, idx, pv, pc, We1, We2, be2, out, nE);
}

// Round 10
// 167.211 us; speedup vs baseline: 1.0545x; 1.0545x over previous
//
#include <hip/hip_runtime.h>

typedef float  f32x2  __attribute__((ext_vector_type(2)));
typedef float  f32x4  __attribute__((ext_vector_type(4)));
typedef float  f32x16 __attribute__((ext_vector_type(16)));
typedef short  s16x4  __attribute__((ext_vector_type(4)));
typedef short  s16x8  __attribute__((ext_vector_type(8)));
typedef unsigned int u32x2 __attribute__((ext_vector_type(2)));

__device__ __forceinline__ unsigned f2bf(float f) {
    unsigned u = __builtin_bit_cast(unsigned, f);
    u += 0x7FFFu + ((u >> 16) & 1u);   // RNE
    return u >> 16;
}
__device__ __forceinline__ s16x4 pack4(float a, float b, float c, float d) {
    u32x2 u;
    u[0] = f2bf(a) | (f2bf(b) << 16);
    u[1] = f2bf(c) | (f2bf(d) << 16);
    return __builtin_bit_cast(s16x4, u);
}
__device__ __forceinline__ s16x4 pack4v(f32x4 v) { return pack4(v[0], v[1], v[2], v[3]); }
__device__ __forceinline__ s16x4 lo4(s16x8 v) { return __builtin_shufflevector(v, v, 0, 1, 2, 3); }
__device__ __forceinline__ s16x4 hi4(s16x8 v) { return __builtin_shufflevector(v, v, 4, 5, 6, 7); }

// ---------------------------------------------------------------------------
// Node MLP (unchanged, proven): P = relu(relu(X W1^T+b1) W2^T+b2) Wm^T (+ bm),
// bf16 out, natural channel layout P[node*32+ch]. 32x32x8 MFMA path.
// ---------------------------------------------------------------------------
__device__ __forceinline__ void node_body(
    const float* __restrict__ X,
    const float* __restrict__ W1, const float* __restrict__ b1,
    const float* __restrict__ W2, const float* __restrict__ b2,
    const float* __restrict__ Wm, const float* __restrict__ bm,
    unsigned short* __restrict__ outp, int N, int tile0)
{
    const int lane = threadIdx.x & 63;
    const int g = lane >> 5, m = lane & 31;
    const int ntile = (N + 31) >> 5;
    if (tile0 >= ntile) return;

    s16x4 a1[4], a2[4], am[4];
#pragma unroll
    for (int q = 0; q < 4; ++q) {
        const float* p1 = W1 + m * 32 + 8 * q + 4 * g;
        a1[q] = pack4(p1[0], p1[1], p1[2], p1[3]);
        const float* p2 = W2 + m * 32 + 8 * q + 4 * g;
        a2[q] = pack4(p2[0], p2[1], p2[2], p2[3]);
        const float* pm = Wm + m * 96 + 8 * q + 4 * g;
        am[q] = pack4(pm[0], pm[1], pm[2], pm[3]);
    }
    f32x16 f1, f2, f3;
#pragma unroll
    for (int r = 0; r < 16; ++r) {
        int ch = (r & 3) + 8 * (r >> 2) + 4 * g;
        f1[r] = b1[ch];
        f2[r] = b2[ch];
        f3[r] = bm ? bm[ch] : 0.f;
    }

#pragma unroll
    for (int k = 0; k < 4; ++k) {
        const int tile = tile0 + k;
        if (tile >= ntile) break;
        const int node0 = tile * 32 + m;
        const int node = node0 < N ? node0 : N - 1;

        s16x4 bX[4];
#pragma unroll
        for (int q = 0; q < 4; ++q) {
            f32x4 v = *reinterpret_cast<const f32x4*>(X + (size_t)node * 32 + 8 * q + 4 * g);
            bX[q] = pack4v(v);
        }
        f32x16 acc = f1;
#pragma unroll
        for (int q = 0; q < 4; ++q) acc = __builtin_amdgcn_mfma_f32_32x32x8bf16_1k(a1[q], bX[q], acc, 0, 0, 0);
        s16x4 bH[4];
#pragma unroll
        for (int q = 0; q < 4; ++q)
            bH[q] = pack4(fmaxf(acc[4*q+0], 0.f), fmaxf(acc[4*q+1], 0.f),
                          fmaxf(acc[4*q+2], 0.f), fmaxf(acc[4*q+3], 0.f));
        acc = f2;
#pragma unroll
        for (int q = 0; q < 4; ++q) acc = __builtin_amdgcn_mfma_f32_32x32x8bf16_1k(a2[q], bH[q], acc, 0, 0, 0);
#pragma unroll
        for (int q = 0; q < 4; ++q)
            bH[q] = pack4(fmaxf(acc[4*q+0], 0.f), fmaxf(acc[4*q+1], 0.f),
                          fmaxf(acc[4*q+2], 0.f), fmaxf(acc[4*q+3], 0.f));
        acc = f3;
#pragma unroll
        for (int q = 0; q < 4; ++q) acc = __builtin_amdgcn_mfma_f32_32x32x8bf16_1k(am[q], bH[q], acc, 0, 0, 0);

        if (node0 < N) {
#pragma unroll
            for (int q = 0; q < 4; ++q) {
                s16x4 o = pack4(acc[4*q+0], acc[4*q+1], acc[4*q+2], acc[4*q+3]);
                *reinterpret_cast<s16x4*>(outp + (size_t)node0 * 32 + 8 * q + 4 * g) = o;
            }
        }
    }
}

__global__ __launch_bounds__(256) void nodes_kernel(
    const float* __restrict__ var_f, const float* __restrict__ con_f,
    const float* __restrict__ Wv1, const float* __restrict__ bv1,
    const float* __restrict__ Wv2, const float* __restrict__ bv2,
    const float* __restrict__ Wc1, const float* __restrict__ bc1,
    const float* __restrict__ Wc2, const float* __restrict__ bc2,
    const float* __restrict__ We1, const float* __restrict__ be1,
    unsigned short* __restrict__ pv, unsigned short* __restrict__ pc,
    int nV, int nC, int wavesV)
{
    const int wvg = (blockIdx.x * blockDim.x + threadIdx.x) >> 6;
    if (wvg < wavesV) {
        node_body(var_f, Wv1, bv1, Wv2, bv2, We1 + 32, be1, pv, nV, wvg * 4);
    } else {
        node_body(con_f, Wc1, bc1, Wc2, bc2, We1 + 64, nullptr, pc, nC,
                  (wvg - wavesV) * 4);
    }
}

// ---------------------------------------------------------------------------
// Edge kernel, 16x16x16 edges-as-columns (R8 base, R8 LDS store path) with a
// DEPTH-2 software pipeline: two raw register stages A/B, ping-pong by loop
// unroll. The phase computing tile t consumes its stage (Ef packed inline,
// pv/pc consumed raw), then refills the SAME stage with loads for t+2nw and
// issues idx for t+4nw. Every load gets ~1.7 iterations of slack and the wave
// keeps 12-28 loads in flight at all times (no vmcnt(0) drain point).
// ---------------------------------------------------------------------------
#define EDGE_PHASE(P_ef00, P_ef01, P_ef10, P_ef11, P_pv0, P_pv1, P_pc0, P_pc1, \
                   IX00, IX01, IX10, IX11, tcur)                               \
    {                                                                          \
        const int t_ = (tcur);                                                 \
        /* pack Ef inline (waits this stage's loads; other stage stays in flight) */ \
        s16x4 eb00 = pack4v(P_ef00), eb01 = pack4v(P_ef01);                    \
        s16x4 eb10 = pack4v(P_ef10), eb11 = pack4v(P_ef11);                    \
        f32x4 a00 = {}, a01 = {}, a10 = {}, a11 = {};                          \
        a00 = __builtin_amdgcn_mfma_f32_16x16x16bf16_1k(aW1[0][0], eb00, a00, 0, 0, 0); \
        a01 = __builtin_amdgcn_mfma_f32_16x16x16bf16_1k(aW1[0][0], eb10, a01, 0, 0, 0); \
        a10 = __builtin_amdgcn_mfma_f32_16x16x16bf16_1k(aW1[1][0], eb00, a10, 0, 0, 0); \
        a11 = __builtin_amdgcn_mfma_f32_16x16x16bf16_1k(aW1[1][0], eb10, a11, 0, 0, 0); \
        a00 = __builtin_amdgcn_mfma_f32_16x16x16bf16_1k(aW1[0][1], eb01, a00, 0, 0, 0); \
        a01 = __builtin_amdgcn_mfma_f32_16x16x16bf16_1k(aW1[0][1], eb11, a01, 0, 0, 0); \
        a10 = __builtin_amdgcn_mfma_f32_16x16x16bf16_1k(aW1[1][1], eb01, a10, 0, 0, 0); \
        a11 = __builtin_amdgcn_mfma_f32_16x16x16bf16_1k(aW1[1][1], eb11, a11, 0, 0, 0); \
        a00 = __builtin_amdgcn_mfma_f32_16x16x16bf16_1k(aP[0][0], lo4(P_pv0), a00, 0, 0, 0); \
        a00 = __builtin_amdgcn_mfma_f32_16x16x16bf16_1k(aP[0][1], hi4(P_pv0), a00, 0, 0, 0); \
        a01 = __builtin_amdgcn_mfma_f32_16x16x16bf16_1k(aP[0][0], lo4(P_pv1), a01, 0, 0, 0); \
        a01 = __builtin_amdgcn_mfma_f32_16x16x16bf16_1k(aP[0][1], hi4(P_pv1), a01, 0, 0, 0); \
        a10 = __builtin_amdgcn_mfma_f32_16x16x16bf16_1k(aP[1][0], lo4(P_pv0), a10, 0, 0, 0); \
        a10 = __builtin_amdgcn_mfma_f32_16x16x16bf16_1k(aP[1][1], hi4(P_pv0), a10, 0, 0, 0); \
        a11 = __builtin_amdgcn_mfma_f32_16x16x16bf16_1k(aP[1][0], lo4(P_pv1), a11, 0, 0, 0); \
        a11 = __builtin_amdgcn_mfma_f32_16x16x16bf16_1k(aP[1][1], hi4(P_pv1), a11, 0, 0, 0); \
        a00 = __builtin_amdgcn_mfma_f32_16x16x16bf16_1k(aP[0][0], lo4(P_pc0), a00, 0, 0, 0); \
        a00 = __builtin_amdgcn_mfma_f32_16x16x16bf16_1k(aP[0][1], hi4(P_pc0), a00, 0, 0, 0); \
        a01 = __builtin_amdgcn_mfma_f32_16x16x16bf16_1k(aP[0][0], lo4(P_pc1), a01, 0, 0, 0); \
        a01 = __builtin_amdgcn_mfma_f32_16x16x16bf16_1k(aP[0][1], hi4(P_pc1), a01, 0, 0, 0); \
        a10 = __builtin_amdgcn_mfma_f32_16x16x16bf16_1k(aP[1][0], lo4(P_pc0), a10, 0, 0, 0); \
        a10 = __builtin_amdgcn_mfma_f32_16x16x16bf16_1k(aP[1][1], hi4(P_pc0), a10, 0, 0, 0); \
        a11 = __builtin_amdgcn_mfma_f32_16x16x16bf16_1k(aP[1][0], lo4(P_pc1), a11, 0, 0, 0); \
        a11 = __builtin_amdgcn_mfma_f32_16x16x16bf16_1k(aP[1][1], hi4(P_pc1), a11, 0, 0, 0); \
        s16x4 bH00 = pack4(fmaxf(a00[0], 0.f), fmaxf(a00[1], 0.f), fmaxf(a00[2], 0.f), fmaxf(a00[3], 0.f)); \
        s16x4 bH01 = pack4(fmaxf(a10[0], 0.f), fmaxf(a10[1], 0.f), fmaxf(a10[2], 0.f), fmaxf(a10[3], 0.f)); \
        s16x4 bH10 = pack4(fmaxf(a01[0], 0.f), fmaxf(a01[1], 0.f), fmaxf(a01[2], 0.f), fmaxf(a01[3], 0.f)); \
        s16x4 bH11 = pack4(fmaxf(a11[0], 0.f), fmaxf(a11[1], 0.f), fmaxf(a11[2], 0.f), fmaxf(a11[3], 0.f)); \
        f32x4 o00 = b2f[0], o01 = b2f[0], o10 = b2f[1], o11 = b2f[1];          \
        o00 = __builtin_amdgcn_mfma_f32_16x16x16bf16_1k(aW2[0][0], bH00, o00, 0, 0, 0); \
        o01 = __builtin_amdgcn_mfma_f32_16x16x16bf16_1k(aW2[0][0], bH10, o01, 0, 0, 0); \
        o10 = __builtin_amdgcn_mfma_f32_16x16x16bf16_1k(aW2[1][0], bH00, o10, 0, 0, 0); \
        o11 = __builtin_amdgcn_mfma_f32_16x16x16bf16_1k(aW2[1][0], bH10, o11, 0, 0, 0); \
        o00 = __builtin_amdgcn_mfma_f32_16x16x16bf16_1k(aW2[0][1], bH01, o00, 0, 0, 0); \
        o01 = __builtin_amdgcn_mfma_f32_16x16x16bf16_1k(aW2[0][1], bH11, o01, 0, 0, 0); \
        o10 = __builtin_amdgcn_mfma_f32_16x16x16bf16_1k(aW2[1][1], bH01, o10, 0, 0, 0); \
        o11 = __builtin_amdgcn_mfma_f32_16x16x16bf16_1k(aW2[1][1], bH11, o11, 0, 0, 0); \
        /* refill this stage: loads for t+2nw (gathers use IX, loaded 2 phases ago) */ \
        {                                                                      \
            int tf = t_ + 2 * nw; if (tf >= ntile) tf = ntile - 1;             \
            P_ef00 = *reinterpret_cast<const f32x4*>(Ef + (size_t)(tf * 32 + m) * 32 + 4 * c); \
            P_ef01 = *reinterpret_cast<const f32x4*>(Ef + (size_t)(tf * 32 + m) * 32 + 16 + 4 * c); \
            P_ef10 = *reinterpret_cast<const f32x4*>(Ef + (size_t)(tf * 32 + 16 + m) * 32 + 4 * c); \
            P_ef11 = *reinterpret_cast<const f32x4*>(Ef + (size_t)(tf * 32 + 16 + m) * 32 + 16 + 4 * c); \
            P_pv0 = *reinterpret_cast<const s16x8*>(pv + (size_t)IX00 * 32 + 8 * c); \
            P_pv1 = *reinterpret_cast<const s16x8*>(pv + (size_t)IX01 * 32 + 8 * c); \
            P_pc0 = *reinterpret_cast<const s16x8*>(pc + (size_t)IX10 * 32 + 8 * c); \
            P_pc1 = *reinterpret_cast<const s16x8*>(pc + (size_t)IX11 * 32 + 8 * c); \
            int ti = t_ + 4 * nw; if (ti >= ntile) ti = ntile - 1;             \
            IX00 = idx[ti * 32 + m];        IX01 = idx[ti * 32 + 16 + m];      \
            IX10 = idx[nE + ti * 32 + m];   IX11 = idx[nE + ti * 32 + 16 + m]; \
        }                                                                      \
        /* store: LDS transpose (stride 34) then coalesced NT stores */        \
        {                                                                      \
            float* p_ = ldsw + (size_t)m * 34 + 4 * c;                         \
            *reinterpret_cast<f32x2*>(p_)      = f32x2{o00[0], o00[1]};        \
            *reinterpret_cast<f32x2*>(p_ + 2)  = f32x2{o00[2], o00[3]};        \
            *reinterpret_cast<f32x2*>(p_ + 16) = f32x2{o10[0], o10[1]};        \
            *reinterpret_cast<f32x2*>(p_ + 18) = f32x2{o10[2], o10[3]};        \
            float* q_ = ldsw + (size_t)(16 + m) * 34 + 4 * c;                  \
            *reinterpret_cast<f32x2*>(q_)      = f32x2{o01[0], o01[1]};        \
            *reinterpret_cast<f32x2*>(q_ + 2)  = f32x2{o01[2], o01[3]};        \
            *reinterpret_cast<f32x2*>(q_ + 16) = f32x2{o11[0], o11[1]};        \
            *reinterpret_cast<f32x2*>(q_ + 18) = f32x2{o11[2], o11[3]};        \
            float* obase = out + (size_t)t_ * 1024;                            \
            _Pragma("unroll")                                                  \
            for (int p = 0; p < 4; ++p) {                                      \
                int li = p * 256 + lane * 4;                                   \
                int row = li >> 5, col = li & 31;                              \
                const float* s_ = ldsw + (size_t)row * 34 + col;               \
                f32x2 lo_ = *reinterpret_cast<const f32x2*>(s_);               \
                f32x2 hi_ = *reinterpret_cast<const f32x2*>(s_ + 2);           \
                f32x4 v_; v_[0] = lo_[0]; v_[1] = lo_[1]; v_[2] = hi_[0]; v_[3] = hi_[1]; \
                __builtin_nontemporal_store(v_, reinterpret_cast<f32x4*>(obase + li)); \
            }                                                                  \
        }                                                                      \
    }

__global__ __launch_bounds__(256, 4) void edge_kernel(
    const float* __restrict__ Ef, const int* __restrict__ idx,
    const unsigned short* __restrict__ pv, const unsigned short* __restrict__ pc,
    const float* __restrict__ We1, const float* __restrict__ We2,
    const float* __restrict__ be2,
    float* __restrict__ out, int nE)
{
    __shared__ float ldso[4 * 1088];          // 4 waves * 32 rows * stride 34
    const int lane = threadIdx.x & 63;
    const int wv = threadIdx.x >> 6;
    const int m = lane & 15, c = lane >> 4;   // 16x16 frag coords
    float* ldsw = ldso + wv * 1088;

    // Weight fragments (16x16x16): A[row=l%16][k=4c+j].
    s16x4 aW1[2][2], aP[2][2], aW2[2][2];
    f32x4 b2f[2];
#pragma unroll
    for (int r = 0; r < 2; ++r) {
#pragma unroll
        for (int kk = 0; kk < 2; ++kk) {
            const float* p1 = We1 + (16 * r + m) * 96 + 16 * kk + 4 * c;
            aW1[r][kk] = pack4(p1[0], p1[1], p1[2], p1[3]);
            const float* p2 = We2 + (16 * r + m) * 32 + 16 * kk + 4 * c;
            aW2[r][kk] = pack4(p2[0], p2[1], p2[2], p2[3]);
            const int j_hit = 16 * r + m - 8 * c - 4 * kk;
            s16x4 w;
#pragma unroll
            for (int j = 0; j < 4; ++j) w[j] = (short)((j == j_hit) ? 0x3F80 : 0);
            aP[r][kk] = w;
        }
        f32x4 b;
#pragma unroll
        for (int j = 0; j < 4; ++j) b[j] = be2[16 * r + 4 * c + j];
        b2f[r] = b;
    }

    const int ntile = nE >> 5;
    const int nw = (gridDim.x * blockDim.x) >> 6;
    int t = (blockIdx.x * blockDim.x + threadIdx.x) >> 6;
    if (t >= ntile) return;

    // ---- prologue: fill A(t), B(t+nw); idx chain ia=idx(t+2nw), ib=idx(t+3nw)
    f32x4 Aef00, Aef01, Aef10, Aef11, Bef00, Bef01, Bef10, Bef11;
    s16x8 Apv0, Apv1, Apc0, Apc1, Bpv0, Bpv1, Bpc0, Bpc1;
    int ia00, ia01, ia10, ia11, ib00, ib01, ib10, ib11;
    {
        const int t0 = t;
        int t1 = t + nw;     if (t1 >= ntile) t1 = ntile - 1;
        int j000 = idx[t0 * 32 + m],      j001 = idx[t0 * 32 + 16 + m];
        int j010 = idx[nE + t0 * 32 + m], j011 = idx[nE + t0 * 32 + 16 + m];
        int j100 = idx[t1 * 32 + m],      j101 = idx[t1 * 32 + 16 + m];
        int j110 = idx[nE + t1 * 32 + m], j111 = idx[nE + t1 * 32 + 16 + m];
        Aef00 = *reinterpret_cast<const f32x4*>(Ef + (size_t)(t0 * 32 + m) * 32 + 4 * c);
        Aef01 = *reinterpret_cast<const f32x4*>(Ef + (size_t)(t0 * 32 + m) * 32 + 16 + 4 * c);
        Aef10 = *reinterpret_cast<const f32x4*>(Ef + (size_t)(t0 * 32 + 16 + m) * 32 + 4 * c);
        Aef11 = *reinterpret_cast<const f32x4*>(Ef + (size_t)(t0 * 32 + 16 + m) * 32 + 16 + 4 * c);
        Bef00 = *reinterpret_cast<const f32x4*>(Ef + (size_t)(t1 * 32 + m) * 32 + 4 * c);
        Bef01 = *reinterpret_cast<const f32x4*>(Ef + (size_t)(t1 * 32 + m) * 32 + 16 + 4 * c);
        Bef10 = *reinterpret_cast<const f32x4*>(Ef + (size_t)(t1 * 32 + 16 + m) * 32 + 4 * c);
        Bef11 = *reinterpret_cast<const f32x4*>(Ef + (size_t)(t1 * 32 + 16 + m) * 32 + 16 + 4 * c);
        Apv0 = *reinterpret_cast<const s16x8*>(pv + (size_t)j000 * 32 + 8 * c);
        Apv1 = *reinterpret_cast<const s16x8*>(pv + (size_t)j001 * 32 + 8 * c);
        Apc0 = *reinterpret_cast<const s16x8*>(pc + (size_t)j010 * 32 + 8 * c);
        Apc1 = *reinterpret_cast<const s16x8*>(pc + (size_t)j011 * 32 + 8 * c);
        Bpv0 = *reinterpret_cast<const s16x8*>(pv + (size_t)j100 * 32 + 8 * c);
        Bpv1 = *reinterpret_cast<const s16x8*>(pv + (size_t)j101 * 32 + 8 * c);
        Bpc0 = *reinterpret_cast<const s16x8*>(pc + (size_t)j110 * 32 + 8 * c);
        Bpc1 = *reinterpret_cast<const s16x8*>(pc + (size_t)j111 * 32 + 8 * c);
        int t2 = t + 2 * nw; if (t2 >= ntile) t2 = ntile - 1;
        int t3 = t + 3 * nw; if (t3 >= ntile) t3 = ntile - 1;
        ia00 = idx[t2 * 32 + m];      ia01 = idx[t2 * 32 + 16 + m];
        ia10 = idx[nE + t2 * 32 + m]; ia11 = idx[nE + t2 * 32 + 16 + m];
        ib00 = idx[t3 * 32 + m];      ib01 = idx[t3 * 32 + 16 + m];
        ib10 = idx[nE + t3 * 32 + m]; ib11 = idx[nE + t3 * 32 + 16 + m];
    }

    while (true) {
        EDGE_PHASE(Aef00, Aef01, Aef10, Aef11, Apv0, Apv1, Apc0, Apc1,
                   ia00, ia01, ia10, ia11, t);
        if (t + nw >= ntile) break;
        t += nw;
        EDGE_PHASE(Bef00, Bef01, Bef10, Bef11, Bpv0, Bpv1, Bpc0, Bpc1,
                   ib00, ib01, ib10, ib11, t);
        if (t + nw >= ntile) break;
        t += nw;
    }
}

extern "C" void kernel_launch(void* const* d_in, const int* in_sizes, int n_in,
                              void* d_out, int out_size, void* d_ws, size_t ws_size,
                              hipStream_t stream) {
    const float* var_f = (const float*)d_in[0];
    const float* con_f = (const float*)d_in[1];
    const float* Ef    = (const float*)d_in[2];
    const int*   idx   = (const int*)d_in[3];
    const float* Wv1 = (const float*)d_in[4];
    const float* bv1 = (const float*)d_in[5];
    const float* Wv2 = (const float*)d_in[6];
    const float* bv2 = (const float*)d_in[7];
    const float* Wc1 = (const float*)d_in[8];
    const float* bc1 = (const float*)d_in[9];
    const float* Wc2 = (const float*)d_in[10];
    const float* bc2 = (const float*)d_in[11];
    const float* We1 = (const float*)d_in[12];
    const float* be1 = (const float*)d_in[13];
    const float* We2 = (const float*)d_in[14];
    const float* be2 = (const float*)d_in[15];
    float* out = (float*)d_out;

    const int nV = in_sizes[0] / 32;
    const int nC = in_sizes[1] / 32;
    const int nE = in_sizes[2] / 32;

    unsigned short* pv = (unsigned short*)d_ws;
    unsigned short* pc = pv + (size_t)nV * 32;

    const int wavesV = (((nV + 31) >> 5) + 3) >> 2;
    const int wavesC = (((nC + 31) >> 5) + 3) >> 2;
    const int nodeBlocks = (wavesV + wavesC + 3) / 4;
    nodes_kernel<<<nodeBlocks, 256, 0, stream>>>(
        var_f, con_f, Wv1, bv1, Wv2, bv2, Wc1, bc1, Wc2, bc2,
        We1, be1, pv, pc, nV, nC, wavesV);

    edge_kernel<<<1024, 256, 0, stream>>>(Ef, idx, pv, pc, We1, We2, be2, out, nE);
}

// Round 11
// 158.088 us; speedup vs baseline: 1.1153x; 1.0577x over previous
//
#include <hip/hip_runtime.h>

typedef float  f32x2  __attribute__((ext_vector_type(2)));
typedef float  f32x4  __attribute__((ext_vector_type(4)));
typedef float  f32x16 __attribute__((ext_vector_type(16)));
typedef short  s16x4  __attribute__((ext_vector_type(4)));
typedef short  s16x8  __attribute__((ext_vector_type(8)));
typedef unsigned int u32x2 __attribute__((ext_vector_type(2)));

__device__ __forceinline__ unsigned f2bf(float f) {
    unsigned u = __builtin_bit_cast(unsigned, f);
    u += 0x7FFFu + ((u >> 16) & 1u);   // RNE
    return u >> 16;
}
__device__ __forceinline__ s16x4 pack4(float a, float b, float c, float d) {
    u32x2 u;
    u[0] = f2bf(a) | (f2bf(b) << 16);
    u[1] = f2bf(c) | (f2bf(d) << 16);
    return __builtin_bit_cast(s16x4, u);
}
__device__ __forceinline__ s16x4 pack4v(f32x4 v) { return pack4(v[0], v[1], v[2], v[3]); }
__device__ __forceinline__ s16x4 lo4(s16x8 v) { return __builtin_shufflevector(v, v, 0, 1, 2, 3); }
__device__ __forceinline__ s16x4 hi4(s16x8 v) { return __builtin_shufflevector(v, v, 4, 5, 6, 7); }

// ---------------------------------------------------------------------------
// Node MLP (proven): P = relu(relu(X W1^T+b1) W2^T+b2) Wm^T (+ bm), bf16 out,
// natural channel layout P[node*32+ch]. 32x32x8 MFMA path.
// ---------------------------------------------------------------------------
__device__ __forceinline__ void node_body(
    const float* __restrict__ X,
    const float* __restrict__ W1, const float* __restrict__ b1,
    const float* __restrict__ W2, const float* __restrict__ b2,
    const float* __restrict__ Wm, const float* __restrict__ bm,
    unsigned short* __restrict__ outp, int N, int tile0)
{
    const int lane = threadIdx.x & 63;
    const int g = lane >> 5, m = lane & 31;
    const int ntile = (N + 31) >> 5;
    if (tile0 >= ntile) return;

    s16x4 a1[4], a2[4], am[4];
#pragma unroll
    for (int q = 0; q < 4; ++q) {
        const float* p1 = W1 + m * 32 + 8 * q + 4 * g;
        a1[q] = pack4(p1[0], p1[1], p1[2], p1[3]);
        const float* p2 = W2 + m * 32 + 8 * q + 4 * g;
        a2[q] = pack4(p2[0], p2[1], p2[2], p2[3]);
        const float* pm = Wm + m * 96 + 8 * q + 4 * g;
        am[q] = pack4(pm[0], pm[1], pm[2], pm[3]);
    }
    f32x16 f1, f2, f3;
#pragma unroll
    for (int r = 0; r < 16; ++r) {
        int ch = (r & 3) + 8 * (r >> 2) + 4 * g;
        f1[r] = b1[ch];
        f2[r] = b2[ch];
        f3[r] = bm ? bm[ch] : 0.f;
    }

#pragma unroll
    for (int k = 0; k < 4; ++k) {
        const int tile = tile0 + k;
        if (tile >= ntile) break;
        const int node0 = tile * 32 + m;
        const int node = node0 < N ? node0 : N - 1;

        s16x4 bX[4];
#pragma unroll
        for (int q = 0; q < 4; ++q) {
            f32x4 v = *reinterpret_cast<const f32x4*>(X + (size_t)node * 32 + 8 * q + 4 * g);
            bX[q] = pack4v(v);
        }
        f32x16 acc = f1;
#pragma unroll
        for (int q = 0; q < 4; ++q) acc = __builtin_amdgcn_mfma_f32_32x32x8bf16_1k(a1[q], bX[q], acc, 0, 0, 0);
        s16x4 bH[4];
#pragma unroll
        for (int q = 0; q < 4; ++q)
            bH[q] = pack4(fmaxf(acc[4*q+0], 0.f), fmaxf(acc[4*q+1], 0.f),
                          fmaxf(acc[4*q+2], 0.f), fmaxf(acc[4*q+3], 0.f));
        acc = f2;
#pragma unroll
        for (int q = 0; q < 4; ++q) acc = __builtin_amdgcn_mfma_f32_32x32x8bf16_1k(a2[q], bH[q], acc, 0, 0, 0);
#pragma unroll
        for (int q = 0; q < 4; ++q)
            bH[q] = pack4(fmaxf(acc[4*q+0], 0.f), fmaxf(acc[4*q+1], 0.f),
                          fmaxf(acc[4*q+2], 0.f), fmaxf(acc[4*q+3], 0.f));
        acc = f3;
#pragma unroll
        for (int q = 0; q < 4; ++q) acc = __builtin_amdgcn_mfma_f32_32x32x8bf16_1k(am[q], bH[q], acc, 0, 0, 0);

        if (node0 < N) {
#pragma unroll
            for (int q = 0; q < 4; ++q) {
                s16x4 o = pack4(acc[4*q+0], acc[4*q+1], acc[4*q+2], acc[4*q+3]);
                *reinterpret_cast<s16x4*>(outp + (size_t)node0 * 32 + 8 * q + 4 * g) = o;
            }
        }
    }
}

__global__ __launch_bounds__(256) void nodes_kernel(
    const float* __restrict__ var_f, const float* __restrict__ con_f,
    const float* __restrict__ Wv1, const float* __restrict__ bv1,
    const float* __restrict__ Wv2, const float* __restrict__ bv2,
    const float* __restrict__ Wc1, const float* __restrict__ bc1,
    const float* __restrict__ Wc2, const float* __restrict__ bc2,
    const float* __restrict__ We1, const float* __restrict__ be1,
    unsigned short* __restrict__ pv, unsigned short* __restrict__ pc,
    int nV, int nC, int wavesV)
{
    const int wvg = (blockIdx.x * blockDim.x + threadIdx.x) >> 6;
    if (wvg < wavesV) {
        node_body(var_f, Wv1, bv1, Wv2, bv2, We1 + 32, be1, pv, nV, wvg * 4);
    } else {
        node_body(con_f, Wc1, bc1, Wc2, bc2, We1 + 64, nullptr, pc, nC,
                  (wvg - wavesV) * 4);
    }
}

// ---------------------------------------------------------------------------
// Edge kernel (R8, best measured: 150 us, 4.03 TB/s): 16x16x16 MFMA,
// edges-as-COLUMNS. All loads/gathers fully line-coalesced (4 lanes per 64B
// line); depth-1 pipeline (Ef/gathers/idx one tile ahead); LDS store
// transpose (stride 34) -> full-line coalesced NT stores.
// ---------------------------------------------------------------------------
__global__ __launch_bounds__(256, 4) void edge_kernel(
    const float* __restrict__ Ef, const int* __restrict__ idx,
    const unsigned short* __restrict__ pv, const unsigned short* __restrict__ pc,
    const float* __restrict__ We1, const float* __restrict__ We2,
    const float* __restrict__ be2,
    float* __restrict__ out, int nE)
{
    __shared__ float ldso[4 * 1088];          // 4 waves * 32 rows * stride 34
    const int lane = threadIdx.x & 63;
    const int wv = threadIdx.x >> 6;
    const int m = lane & 15, c = lane >> 4;   // 16x16 frag coords
    float* ldsw = ldso + wv * 1088;

    // Weight fragments (16x16x16): A[row=l%16][k=4c+j].
    s16x4 aW1[2][2], aP[2][2], aW2[2][2];
    f32x4 b2f[2];
#pragma unroll
    for (int r = 0; r < 2; ++r) {
#pragma unroll
        for (int kk = 0; kk < 2; ++kk) {
            const float* p1 = We1 + (16 * r + m) * 96 + 16 * kk + 4 * c;
            aW1[r][kk] = pack4(p1[0], p1[1], p1[2], p1[3]);
            const float* p2 = We2 + (16 * r + m) * 32 + 16 * kk + 4 * c;
            aW2[r][kk] = pack4(p2[0], p2[1], p2[2], p2[3]);
            const int j_hit = 16 * r + m - 8 * c - 4 * kk;
            s16x4 w;
#pragma unroll
            for (int j = 0; j < 4; ++j) w[j] = (short)((j == j_hit) ? 0x3F80 : 0);
            aP[r][kk] = w;
        }
        f32x4 b;
#pragma unroll
        for (int j = 0; j < 4; ++j) b[j] = be2[16 * r + 4 * c + j];
        b2f[r] = b;
    }

    const int ntile = nE >> 5;
    const int nw = (gridDim.x * blockDim.x) >> 6;
    int t = (blockIdx.x * blockDim.x + threadIdx.x) >> 6;
    if (t >= ntile) return;

    // ---- prologue: stage tile t ----
    int ib0[2], ib1[2];          // idx for the NEXT staged tile
    s16x4 ebf[2][2];             // Ef bf16 frags, current tile
    s16x8 pvf[2], pcf[2];        // gathered partials, current tile
    {
        int i0[2], i1[2];
#pragma unroll
        for (int e = 0; e < 2; ++e) {
            i0[e] = idx[t * 32 + 16 * e + m];
            i1[e] = idx[nE + t * 32 + 16 * e + m];
        }
#pragma unroll
        for (int e = 0; e < 2; ++e) {
#pragma unroll
            for (int kk = 0; kk < 2; ++kk) {
                f32x4 v = *reinterpret_cast<const f32x4*>(
                    Ef + (size_t)(t * 32 + 16 * e + m) * 32 + 16 * kk + 4 * c);
                ebf[e][kk] = pack4v(v);
            }
            pvf[e] = *reinterpret_cast<const s16x8*>(pv + (size_t)i0[e] * 32 + 8 * c);
            pcf[e] = *reinterpret_cast<const s16x8*>(pc + (size_t)i1[e] * 32 + 8 * c);
        }
        int t1 = (t + nw < ntile) ? t + nw : t;
#pragma unroll
        for (int e = 0; e < 2; ++e) {
            ib0[e] = idx[t1 * 32 + 16 * e + m];
            ib1[e] = idx[nE + t1 * 32 + 16 * e + m];
        }
    }

    while (true) {
        const int tn = t + nw;
        const int tc = tn < ntile ? tn : t;

        // ---- issue stage(t+nw): Ef (f32), gathers, idx(t+2nw) ----
        f32x4 nef[2][2];
        s16x8 npv[2], npc[2];
        int ic0[2], ic1[2];
#pragma unroll
        for (int e = 0; e < 2; ++e) {
#pragma unroll
            for (int kk = 0; kk < 2; ++kk)
                nef[e][kk] = *reinterpret_cast<const f32x4*>(
                    Ef + (size_t)(tc * 32 + 16 * e + m) * 32 + 16 * kk + 4 * c);
            npv[e] = *reinterpret_cast<const s16x8*>(pv + (size_t)ib0[e] * 32 + 8 * c);
            npc[e] = *reinterpret_cast<const s16x8*>(pc + (size_t)ib1[e] * 32 + 8 * c);
        }
        {
            int t2 = (tn + nw < ntile) ? tn + nw : tc;
#pragma unroll
            for (int e = 0; e < 2; ++e) {
                ic0[e] = idx[t2 * 32 + 16 * e + m];
                ic1[e] = idx[nE + t2 * 32 + 16 * e + m];
            }
        }

        // ---- layer 1: acc[r][e], K=96 (Ef 2kk + pv perm + pc perm) ----
        f32x4 a00 = {}, a01 = {}, a10 = {}, a11 = {};
        a00 = __builtin_amdgcn_mfma_f32_16x16x16bf16_1k(aW1[0][0], ebf[0][0], a00, 0, 0, 0);
        a01 = __builtin_amdgcn_mfma_f32_16x16x16bf16_1k(aW1[0][0], ebf[1][0], a01, 0, 0, 0);
        a10 = __builtin_amdgcn_mfma_f32_16x16x16bf16_1k(aW1[1][0], ebf[0][0], a10, 0, 0, 0);
        a11 = __builtin_amdgcn_mfma_f32_16x16x16bf16_1k(aW1[1][0], ebf[1][0], a11, 0, 0, 0);
        a00 = __builtin_amdgcn_mfma_f32_16x16x16bf16_1k(aW1[0][1], ebf[0][1], a00, 0, 0, 0);
        a01 = __builtin_amdgcn_mfma_f32_16x16x16bf16_1k(aW1[0][1], ebf[1][1], a01, 0, 0, 0);
        a10 = __builtin_amdgcn_mfma_f32_16x16x16bf16_1k(aW1[1][1], ebf[0][1], a10, 0, 0, 0);
        a11 = __builtin_amdgcn_mfma_f32_16x16x16bf16_1k(aW1[1][1], ebf[1][1], a11, 0, 0, 0);
        a00 = __builtin_amdgcn_mfma_f32_16x16x16bf16_1k(aP[0][0], lo4(pvf[0]), a00, 0, 0, 0);
        a00 = __builtin_amdgcn_mfma_f32_16x16x16bf16_1k(aP[0][1], hi4(pvf[0]), a00, 0, 0, 0);
        a01 = __builtin_amdgcn_mfma_f32_16x16x16bf16_1k(aP[0][0], lo4(pvf[1]), a01, 0, 0, 0);
        a01 = __builtin_amdgcn_mfma_f32_16x16x16bf16_1k(aP[0][1], hi4(pvf[1]), a01, 0, 0, 0);
        a10 = __builtin_amdgcn_mfma_f32_16x16x16bf16_1k(aP[1][0], lo4(pvf[0]), a10, 0, 0, 0);
        a10 = __builtin_amdgcn_mfma_f32_16x16x16bf16_1k(aP[1][1], hi4(pvf[0]), a10, 0, 0, 0);
        a11 = __builtin_amdgcn_mfma_f32_16x16x16bf16_1k(aP[1][0], lo4(pvf[1]), a11, 0, 0, 0);
        a11 = __builtin_amdgcn_mfma_f32_16x16x16bf16_1k(aP[1][1], hi4(pvf[1]), a11, 0, 0, 0);
        a00 = __builtin_amdgcn_mfma_f32_16x16x16bf16_1k(aP[0][0], lo4(pcf[0]), a00, 0, 0, 0);
        a00 = __builtin_amdgcn_mfma_f32_16x16x16bf16_1k(aP[0][1], hi4(pcf[0]), a00, 0, 0, 0);
        a01 = __builtin_amdgcn_mfma_f32_16x16x16bf16_1k(aP[0][0], lo4(pcf[1]), a01, 0, 0, 0);
        a01 = __builtin_amdgcn_mfma_f32_16x16x16bf16_1k(aP[0][1], hi4(pcf[1]), a01, 0, 0, 0);
        a10 = __builtin_amdgcn_mfma_f32_16x16x16bf16_1k(aP[1][0], lo4(pcf[0]), a10, 0, 0, 0);
        a10 = __builtin_amdgcn_mfma_f32_16x16x16bf16_1k(aP[1][1], hi4(pcf[0]), a10, 0, 0, 0);
        a11 = __builtin_amdgcn_mfma_f32_16x16x16bf16_1k(aP[1][0], lo4(pcf[1]), a11, 0, 0, 0);
        a11 = __builtin_amdgcn_mfma_f32_16x16x16bf16_1k(aP[1][1], hi4(pcf[1]), a11, 0, 0, 0);

        // ---- relu + pack: bH[e][kk] <- acc[r=kk][e] ----
        s16x4 bH00 = pack4(fmaxf(a00[0], 0.f), fmaxf(a00[1], 0.f), fmaxf(a00[2], 0.f), fmaxf(a00[3], 0.f));
        s16x4 bH01 = pack4(fmaxf(a10[0], 0.f), fmaxf(a10[1], 0.f), fmaxf(a10[2], 0.f), fmaxf(a10[3], 0.f));
        s16x4 bH10 = pack4(fmaxf(a01[0], 0.f), fmaxf(a01[1], 0.f), fmaxf(a01[2], 0.f), fmaxf(a01[3], 0.f));
        s16x4 bH11 = pack4(fmaxf(a11[0], 0.f), fmaxf(a11[1], 0.f), fmaxf(a11[2], 0.f), fmaxf(a11[3], 0.f));

        // ---- layer 2: o[r][e] = be2 + We2 * H ----
        f32x4 o00 = b2f[0], o01 = b2f[0], o10 = b2f[1], o11 = b2f[1];
        o00 = __builtin_amdgcn_mfma_f32_16x16x16bf16_1k(aW2[0][0], bH00, o00, 0, 0, 0);
        o01 = __builtin_amdgcn_mfma_f32_16x16x16bf16_1k(aW2[0][0], bH10, o01, 0, 0, 0);
        o10 = __builtin_amdgcn_mfma_f32_16x16x16bf16_1k(aW2[1][0], bH00, o10, 0, 0, 0);
        o11 = __builtin_amdgcn_mfma_f32_16x16x16bf16_1k(aW2[1][0], bH10, o11, 0, 0, 0);
        o00 = __builtin_amdgcn_mfma_f32_16x16x16bf16_1k(aW2[0][1], bH01, o00, 0, 0, 0);
        o01 = __builtin_amdgcn_mfma_f32_16x16x16bf16_1k(aW2[0][1], bH11, o01, 0, 0, 0);
        o10 = __builtin_amdgcn_mfma_f32_16x16x16bf16_1k(aW2[1][1], bH01, o10, 0, 0, 0);
        o11 = __builtin_amdgcn_mfma_f32_16x16x16bf16_1k(aW2[1][1], bH11, o11, 0, 0, 0);

        // ---- store: LDS transpose (stride 34), then coalesced NT stores ----
        {
#pragma unroll
            for (int r = 0; r < 2; ++r) {
#pragma unroll
                for (int e = 0; e < 2; ++e) {
                    f32x4 o = (r == 0) ? (e == 0 ? o00 : o01) : (e == 0 ? o10 : o11);
                    float* p = ldsw + (size_t)(16 * e + m) * 34 + 16 * r + 4 * c;
                    f32x2 lo; lo[0] = o[0]; lo[1] = o[1];
                    f32x2 hi; hi[0] = o[2]; hi[1] = o[3];
                    *reinterpret_cast<f32x2*>(p)     = lo;
                    *reinterpret_cast<f32x2*>(p + 2) = hi;
                }
            }
            float* obase = out + (size_t)t * 1024;
#pragma unroll
            for (int p = 0; p < 4; ++p) {
                int li = p * 256 + lane * 4;
                int row = li >> 5, col = li & 31;
                const float* s = ldsw + (size_t)row * 34 + col;
                f32x2 lo = *reinterpret_cast<const f32x2*>(s);
                f32x2 hi = *reinterpret_cast<const f32x2*>(s + 2);
                f32x4 v; v[0] = lo[0]; v[1] = lo[1]; v[2] = hi[0]; v[3] = hi[1];
                __builtin_nontemporal_store(v, reinterpret_cast<f32x4*>(obase + li));
            }
        }

        if (tn >= ntile) break;
        t = tn;
#pragma unroll
        for (int e = 0; e < 2; ++e) {
#pragma unroll
            for (int kk = 0; kk < 2; ++kk) ebf[e][kk] = pack4v(nef[e][kk]);
            pvf[e] = npv[e]; pcf[e] = npc[e];
            ib0[e] = ic0[e]; ib1[e] = ic1[e];
        }
    }
}

extern "C" void kernel_launch(void* const* d_in, const int* in_sizes, int n_in,
                              void* d_out, int out_size, void* d_ws, size_t ws_size,
                              hipStream_t stream) {
    const float* var_f = (const float*)d_in[0];
    const float* con_f = (const float*)d_in[1];
    const float* Ef    = (const float*)d_in[2];
    const int*   idx   = (const int*)d_in[3];
    const float* Wv1 = (const float*)d_in[4];
    const float* bv1 = (const float*)d_in[5];
    const float* Wv2 = (const float*)d_in[6];
    const float* bv2 = (const float*)d_in[7];
    const float* Wc1 = (const float*)d_in[8];
    const float* bc1 = (const float*)d_in[9];
    const float* Wc2 = (const float*)d_in[10];
    const float* bc2 = (const float*)d_in[11];
    const float* We1 = (const float*)d_in[12];
    const float* be1 = (const float*)d_in[13];
    const float* We2 = (const float*)d_in[14];
    const float* be2 = (const float*)d_in[15];
    float* out = (float*)d_out;

    const int nV = in_sizes[0] / 32;
    const int nC = in_sizes[1] / 32;
    const int nE = in_sizes[2] / 32;

    unsigned short* pv = (unsigned short*)d_ws;
    unsigned short* pc = pv + (size_t)nV * 32;

    const int wavesV = (((nV + 31) >> 5) + 3) >> 2;
    const int wavesC = (((nC + 31) >> 5) + 3) >> 2;
    const int nodeBlocks = (wavesV + wavesC + 3) / 4;
    nodes_kernel<<<nodeBlocks, 256, 0, stream>>>(
        var_f, con_f, Wv1, bv1, Wv2, bv2, Wc1, bc1, Wc2, bc2,
        We1, be1, pv, pc, nV, nC, wavesV);

    edge_kernel<<<1024, 256, 0, stream>>>(Ef, idx, pv, pc, We1, We2, be2, out, nE);
}